// Round 3
// baseline (305.885 us; speedup 1.0000x reference)
//
#include <hip/hip_runtime.h>
#include <hip/hip_bf16.h>
#include <stdint.h>

// RelMHAtt: B=4 S=512 HIDDEN=1024 H=16 D=64 R=64
// Pipeline: convert(fp32->bf16) -> fused [proj GEMM x3 || rel bias] ->
//           attention (register scores) -> out GEMM fp32.
// rel v2: LDS-free operand reads (register blocking 4k x 4h x 16c), LDS only
// for the 4-way c-part reduction. Fused with proj GEMM: GEMM blocks (MFMA-
// bound) and rel blocks (HBM-bound) run concurrently on the CUs.

typedef __attribute__((ext_vector_type(8))) short bf16x8;
typedef __attribute__((ext_vector_type(4))) float f32x4;

__device__ inline unsigned short f2bf(float f) {
    __hip_bfloat16 h = __float2bfloat16(f);
    return *reinterpret_cast<unsigned short*>(&h);
}
__device__ inline float bf2f(unsigned short u) {
    unsigned int t = ((unsigned int)u) << 16;
    return __builtin_bit_cast(float, t);
}

// ---------------------------------------------------------------- convert
// dst layout (bf16): xq[2M] xk[2M] xv[2M] Wq[1M] Wk[1M] Wv[1M] Wm[1M]
__global__ __launch_bounds__(256) void convert_kernel(
    const float* __restrict__ q, const float* __restrict__ k, const float* __restrict__ v,
    const float* __restrict__ wq, const float* __restrict__ wk, const float* __restrict__ wv,
    const float* __restrict__ wm, unsigned short* __restrict__ dst)
{
    const long long X = 2097152LL, Wn = 1048576LL;
    long long e = 4LL * ((long long)blockIdx.x * 256 + threadIdx.x);
    const float* s;
    long long o = e;
    if      (o < X)          { s = q; }
    else if (o < 2*X)        { s = k;  o -= X; }
    else if (o < 3*X)        { s = v;  o -= 2*X; }
    else if (o < 3*X + Wn)   { s = wq; o -= 3*X; }
    else if (o < 3*X + 2*Wn) { s = wk; o -= 3*X + Wn; }
    else if (o < 3*X + 3*Wn) { s = wv; o -= 3*X + 2*Wn; }
    else                     { s = wm; o -= 3*X + 3*Wn; }
    float4 val = *reinterpret_cast<const float4*>(s + o);
    ushort4 u;
    u.x = f2bf(val.x); u.y = f2bf(val.y); u.z = f2bf(val.z); u.w = f2bf(val.w);
    *reinterpret_cast<ushort4*>(dst + e) = u;
}

// ---------------------------------------------------------------- GEMM defs
// C[m,n] = sum_k A[m,k]*B[n,k] + bias[n];  BM=64, BN=128, BK=32; 4 waves.
// mode 0: f32 [M,1024]; 1: bf16 [M,1024]; 2: bf16*0.125; 3: bf16 vht[b][h][d][s]
struct GemmJob { const unsigned short* A; const unsigned short* B; const float* bias; char* C; int mode; };
struct Gemm3 { GemmJob j[3]; };

// ---------------------------------------------------------------- fused proj GEMM + rel
// blocks [0,768): GEMM (z = bid>>8, m = (bid>>3)&31, n = bid&7)
// blocks [768, 768+16384): rel bias
//   biasOut[b][h][q][k] = log(max(dot(rel[b,q,k,:], Wr[h,:]) + br[h], 1e-6))
__global__ __launch_bounds__(256) void gemm_rel(
    Gemm3 g, const float* __restrict__ rel, const float* __restrict__ Wr,
    const float* __restrict__ br, unsigned short* __restrict__ biasT)
{
    __shared__ union SM {
        struct { unsigned short As[2][2048]; unsigned short Bs[2][4096]; } gm;
        float red[4][64][20];   // [cp][k][h(pad 20)]
    } sm;
    int tid = threadIdx.x;

    if (blockIdx.x < 768) {
        // ---------------- GEMM role ----------------
        int bid = blockIdx.x;
        GemmJob jb = g.j[bid >> 8];
        const unsigned short* __restrict__ A = jb.A;
        const unsigned short* __restrict__ B = jb.B;
        int bm0 = ((bid >> 3) & 31) * 64, bn0 = (bid & 7) * 128;
        int wid = tid >> 6, lane = tid & 63;
        int fr = lane & 15, fq = lane >> 4;
        int wm = (wid >> 1) * 32, wn = (wid & 1) * 64;

        f32x4 acc[2][4];
        f32x4 z4 = {0.f, 0.f, 0.f, 0.f};
        for (int i = 0; i < 2; i++) for (int j = 0; j < 4; j++) acc[i][j] = z4;

        auto stage = [&](int buf, int kt) {
            {
                int ci = tid;
                int row = ci >> 2, kc = ci & 3;
                const unsigned short* ga = A + (long long)(bm0 + row) * 1024 + kt * 32 + kc * 8;
                __builtin_amdgcn_global_load_lds((const __attribute__((address_space(1))) void*)ga,
                    (__attribute__((address_space(3))) void*)(&sm.gm.As[buf][ci * 8]), 16, 0, 0);
            }
            #pragma unroll
            for (int i = 0; i < 2; i++) {
                int ci = tid + 256 * i;
                int row = ci >> 2, kc = ci & 3;
                const unsigned short* gb = B + (long long)(bn0 + row) * 1024 + kt * 32 + kc * 8;
                __builtin_amdgcn_global_load_lds((const __attribute__((address_space(1))) void*)gb,
                    (__attribute__((address_space(3))) void*)(&sm.gm.Bs[buf][ci * 8]), 16, 0, 0);
            }
        };
        auto compute = [&](int buf) {
            bf16x8 a[2], b[4];
            #pragma unroll
            for (int fm = 0; fm < 2; fm++)
                a[fm] = *reinterpret_cast<const bf16x8*>(&sm.gm.As[buf][(wm + fm*16 + fr)*32 + fq*8]);
            #pragma unroll
            for (int fn = 0; fn < 4; fn++)
                b[fn] = *reinterpret_cast<const bf16x8*>(&sm.gm.Bs[buf][(wn + fn*16 + fr)*32 + fq*8]);
            #pragma unroll
            for (int fm = 0; fm < 2; fm++)
                #pragma unroll
                for (int fn = 0; fn < 4; fn++)
                    acc[fm][fn] = __builtin_amdgcn_mfma_f32_16x16x32_bf16(a[fm], b[fn], acc[fm][fn], 0, 0, 0);
        };

        stage(0, 0);
        asm volatile("s_waitcnt vmcnt(0)" ::: "memory");
        __syncthreads();
        int cur = 0;
        for (int kt = 0; kt < 31; kt++) {
            stage(cur ^ 1, kt + 1);
            compute(cur);
            asm volatile("s_waitcnt vmcnt(0)" ::: "memory");
            __syncthreads();
            cur ^= 1;
        }
        compute(cur);

        int mode = jb.mode;
        #pragma unroll
        for (int fm = 0; fm < 2; fm++) {
            #pragma unroll
            for (int fn = 0; fn < 4; fn++) {
                int col = bn0 + wn + fn*16 + fr;
                float bv = jb.bias[col];
                f32x4 vacc = acc[fm][fn];
                #pragma unroll
                for (int r = 0; r < 4; r++) {
                    int m = bm0 + wm + fm*16 + fq*4 + r;
                    float val = vacc[r] + bv;
                    if (mode == 0) {
                        reinterpret_cast<float*>(jb.C)[(long long)m*1024 + col] = val;
                    } else if (mode == 1) {
                        reinterpret_cast<unsigned short*>(jb.C)[(long long)m*1024 + col] = f2bf(val);
                    } else if (mode == 2) {
                        reinterpret_cast<unsigned short*>(jb.C)[(long long)m*1024 + col] = f2bf(val * 0.125f);
                    } else {
                        int bb = m >> 9, ss = m & 511;
                        int hh = col >> 6, dd = col & 63;
                        reinterpret_cast<unsigned short*>(jb.C)[(((long long)bb*16 + hh)*64 + dd)*512 + ss] = f2bf(val);
                    }
                }
            }
        }
    } else {
        // ---------------- rel role ----------------
        int rid = blockIdx.x - 768;
        int k0 = (rid & 7) * 64;
        int q  = (rid >> 3) & 511;
        int b  = rid >> 12;
        int cp = tid >> 6, hg = (tid >> 4) & 3, kg = tid & 15;

        const float* rbase = rel + ((long long)(b*512 + q)*512 + k0) * 64 + cp*16;
        float4 rl[4][4];
        #pragma unroll
        for (int kk = 0; kk < 4; kk++)
            #pragma unroll
            for (int j = 0; j < 4; j++)
                rl[kk][j] = *reinterpret_cast<const float4*>(rbase + (kg*4 + kk)*64 + j*4);
        float4 wreg[4][4];
        #pragma unroll
        for (int hh = 0; hh < 4; hh++)
            #pragma unroll
            for (int j = 0; j < 4; j++)
                wreg[hh][j] = *reinterpret_cast<const float4*>(Wr + (hg*4 + hh)*64 + cp*16 + j*4);

        float acc[4][4];
        #pragma unroll
        for (int kk = 0; kk < 4; kk++)
            #pragma unroll
            for (int hh = 0; hh < 4; hh++) acc[kk][hh] = 0.f;
        #pragma unroll
        for (int j = 0; j < 4; j++)
            #pragma unroll
            for (int kk = 0; kk < 4; kk++) {
                float4 r4 = rl[kk][j];
                #pragma unroll
                for (int hh = 0; hh < 4; hh++) {
                    float4 w4 = wreg[hh][j];
                    acc[kk][hh] += r4.x*w4.x + r4.y*w4.y + r4.z*w4.z + r4.w*w4.w;
                }
            }
        // partials -> LDS
        #pragma unroll
        for (int kk = 0; kk < 4; kk++) {
            f32x4 t = {acc[kk][0], acc[kk][1], acc[kk][2], acc[kk][3]};
            *reinterpret_cast<f32x4*>(&sm.red[cp][kg*4 + kk][hg*4]) = t;
        }
        __syncthreads();
        // reduce over cp; thread: h = tid&15, k-quad = tid>>4
        int h = tid & 15, k4 = tid >> 4;
        float brv = br[h];
        ushort4 u4;
        unsigned short* up = reinterpret_cast<unsigned short*>(&u4);
        #pragma unroll
        for (int jj = 0; jj < 4; jj++) {
            int k = k4*4 + jj;
            float s = sm.red[0][k][h] + sm.red[1][k][h] + sm.red[2][k][h] + sm.red[3][k][h] + brv;
            up[jj] = f2bf(__logf(fmaxf(s, 1e-6f)));
        }
        *reinterpret_cast<ushort4*>(biasT + ((long long)(b*16 + h)*512 + q)*512 + k0 + k4*4) = u4;
    }
}

// ---------------------------------------------------------------- final GEMM
__global__ __launch_bounds__(256) void gemm_bt(Gemm3 g)
{
    GemmJob jb = g.j[blockIdx.z];
    const unsigned short* __restrict__ A = jb.A;
    const unsigned short* __restrict__ B = jb.B;
    __shared__ alignas(16) unsigned short As[2][2048];
    __shared__ alignas(16) unsigned short Bs[2][4096];
    int tid = threadIdx.x;
    int bm0 = blockIdx.x * 64, bn0 = blockIdx.y * 128;
    int wid = tid >> 6, lane = tid & 63;
    int fr = lane & 15, fq = lane >> 4;
    int wm = (wid >> 1) * 32, wn = (wid & 1) * 64;

    f32x4 acc[2][4];
    f32x4 z4 = {0.f, 0.f, 0.f, 0.f};
    for (int i = 0; i < 2; i++) for (int j = 0; j < 4; j++) acc[i][j] = z4;

    auto stage = [&](int buf, int kt) {
        {
            int ci = tid;
            int row = ci >> 2, kc = ci & 3;
            const unsigned short* ga = A + (long long)(bm0 + row) * 1024 + kt * 32 + kc * 8;
            __builtin_amdgcn_global_load_lds((const __attribute__((address_space(1))) void*)ga,
                (__attribute__((address_space(3))) void*)(&As[buf][ci * 8]), 16, 0, 0);
        }
        #pragma unroll
        for (int i = 0; i < 2; i++) {
            int ci = tid + 256 * i;
            int row = ci >> 2, kc = ci & 3;
            const unsigned short* gb = B + (long long)(bn0 + row) * 1024 + kt * 32 + kc * 8;
            __builtin_amdgcn_global_load_lds((const __attribute__((address_space(1))) void*)gb,
                (__attribute__((address_space(3))) void*)(&Bs[buf][ci * 8]), 16, 0, 0);
        }
    };
    auto compute = [&](int buf) {
        bf16x8 a[2], b[4];
        #pragma unroll
        for (int fm = 0; fm < 2; fm++)
            a[fm] = *reinterpret_cast<const bf16x8*>(&As[buf][(wm + fm*16 + fr)*32 + fq*8]);
        #pragma unroll
        for (int fn = 0; fn < 4; fn++)
            b[fn] = *reinterpret_cast<const bf16x8*>(&Bs[buf][(wn + fn*16 + fr)*32 + fq*8]);
        #pragma unroll
        for (int fm = 0; fm < 2; fm++)
            #pragma unroll
            for (int fn = 0; fn < 4; fn++)
                acc[fm][fn] = __builtin_amdgcn_mfma_f32_16x16x32_bf16(a[fm], b[fn], acc[fm][fn], 0, 0, 0);
    };

    stage(0, 0);
    asm volatile("s_waitcnt vmcnt(0)" ::: "memory");
    __syncthreads();
    int cur = 0;
    for (int kt = 0; kt < 31; kt++) {
        stage(cur ^ 1, kt + 1);
        compute(cur);
        asm volatile("s_waitcnt vmcnt(0)" ::: "memory");
        __syncthreads();
        cur ^= 1;
    }
    compute(cur);

    int mode = jb.mode;
    #pragma unroll
    for (int fm = 0; fm < 2; fm++) {
        #pragma unroll
        for (int fn = 0; fn < 4; fn++) {
            int col = bn0 + wn + fn*16 + fr;
            float bv = jb.bias[col];
            f32x4 vacc = acc[fm][fn];
            #pragma unroll
            for (int r = 0; r < 4; r++) {
                int m = bm0 + wm + fm*16 + fq*4 + r;
                float val = vacc[r] + bv;
                if (mode == 0) {
                    reinterpret_cast<float*>(jb.C)[(long long)m*1024 + col] = val;
                } else if (mode == 1) {
                    reinterpret_cast<unsigned short*>(jb.C)[(long long)m*1024 + col] = f2bf(val);
                } else if (mode == 2) {
                    reinterpret_cast<unsigned short*>(jb.C)[(long long)m*1024 + col] = f2bf(val * 0.125f);
                } else {
                    int bb = m >> 9, ss = m & 511;
                    int hh = col >> 6, dd = col & 63;
                    reinterpret_cast<unsigned short*>(jb.C)[(((long long)bb*16 + hh)*64 + dd)*512 + ss] = f2bf(val);
                }
            }
        }
    }
}

// ---------------------------------------------------------------- attention
__global__ __launch_bounds__(256) void attn_kernel(
    const unsigned short* __restrict__ qh, const unsigned short* __restrict__ kh,
    const unsigned short* __restrict__ vht, const unsigned short* __restrict__ biasT,
    const unsigned char* __restrict__ mask, unsigned short* __restrict__ atted)
{
    __shared__ alignas(16) unsigned short Pl[16][520];
    __shared__ float pmax[4][16];
    __shared__ float psum[4][16];
    int tid = threadIdx.x;
    int wid = tid >> 6, lane = tid & 63;
    int fr = lane & 15, fq = lane >> 4;
    int q0 = blockIdx.x * 16;
    int h = blockIdx.y, b = blockIdx.z;

    bf16x8 aq[2];
    #pragma unroll
    for (int df = 0; df < 2; df++)
        aq[df] = *reinterpret_cast<const bf16x8*>(
            qh + (long long)(b*512 + q0 + fr)*1024 + h*64 + df*32 + fq*8);

    f32x4 s[8];
    #pragma unroll
    for (int kt = 0; kt < 8; kt++) {
        int cb = wid*128 + kt*16;
        f32x4 a4 = {0.f,0.f,0.f,0.f};
        #pragma unroll
        for (int df = 0; df < 2; df++) {
            bf16x8 bk = *reinterpret_cast<const bf16x8*>(
                kh + (long long)(b*512 + cb + fr)*1024 + h*64 + df*32 + fq*8);
            a4 = __builtin_amdgcn_mfma_f32_16x16x32_bf16(aq[df], bk, a4, 0, 0, 0);
        }
        s[kt] = a4;
    }

    const unsigned short* bbase = biasT + ((long long)(b*16 + h)*512 + q0)*512;
    #pragma unroll
    for (int kt = 0; kt < 8; kt++) {
        int col = wid*128 + kt*16 + fr;
        bool mk = mask[b*512 + col] != 0;
        #pragma unroll
        for (int r = 0; r < 4; r++) {
            float bias = bf2f(bbase[(fq*4 + r)*512 + col]);
            float val = s[kt][r] + bias;
            s[kt][r] = mk ? -1e9f : val;
        }
    }

    float rm[4];
    #pragma unroll
    for (int r = 0; r < 4; r++) {
        float m = s[0][r];
        #pragma unroll
        for (int kt = 1; kt < 8; kt++) m = fmaxf(m, s[kt][r]);
        #pragma unroll
        for (int x = 1; x < 16; x <<= 1) m = fmaxf(m, __shfl_xor(m, x, 64));
        rm[r] = m;
    }
    #pragma unroll
    for (int r = 0; r < 4; r++)
        if (fr == r) pmax[wid][fq*4 + r] = rm[r];
    __syncthreads();
    #pragma unroll
    for (int r = 0; r < 4; r++) {
        float m = pmax[0][fq*4 + r];
        m = fmaxf(m, pmax[1][fq*4 + r]);
        m = fmaxf(m, pmax[2][fq*4 + r]);
        m = fmaxf(m, pmax[3][fq*4 + r]);
        rm[r] = m;
    }

    float sum[4] = {0.f, 0.f, 0.f, 0.f};
    #pragma unroll
    for (int kt = 0; kt < 8; kt++) {
        int col = wid*128 + kt*16 + fr;
        #pragma unroll
        for (int r = 0; r < 4; r++) {
            float p = __expf(s[kt][r] - rm[r]);
            sum[r] += p;
            Pl[fq*4 + r][col] = f2bf(p);
        }
    }
    #pragma unroll
    for (int r = 0; r < 4; r++) {
        float sv = sum[r];
        #pragma unroll
        for (int x = 1; x < 16; x <<= 1) sv += __shfl_xor(sv, x, 64);
        sum[r] = sv;
    }
    #pragma unroll
    for (int r = 0; r < 4; r++)
        if (fr == r) psum[wid][fq*4 + r] = sum[r];
    __syncthreads();
    float sumr[4];
    #pragma unroll
    for (int r = 0; r < 4; r++)
        sumr[r] = psum[0][fq*4+r] + psum[1][fq*4+r] + psum[2][fq*4+r] + psum[3][fq*4+r];

    int d0 = wid * 16;
    f32x4 acco = {0.f,0.f,0.f,0.f};
    for (int c = 0; c < 16; c++) {
        bf16x8 pa = *reinterpret_cast<const bf16x8*>(&Pl[fr][c*32 + fq*8]);
        bf16x8 bv = *reinterpret_cast<const bf16x8*>(
            vht + ((long long)(b*16 + h)*64 + d0 + fr)*512 + c*32 + fq*8);
        acco = __builtin_amdgcn_mfma_f32_16x16x32_bf16(pa, bv, acco, 0, 0, 0);
    }
    #pragma unroll
    for (int r = 0; r < 4; r++) {
        float val = acco[r] / sumr[r];
        atted[(long long)(b*512 + q0 + fq*4 + r)*1024 + h*64 + d0 + fr] = f2bf(val);
    }
}

// ---------------------------------------------------------------- launch
extern "C" void kernel_launch(void* const* d_in, const int* in_sizes, int n_in,
                              void* d_out, int out_size, void* d_ws, size_t ws_size,
                              hipStream_t stream)
{
    const float* v    = (const float*)d_in[0];
    const float* k    = (const float*)d_in[1];
    const float* q    = (const float*)d_in[2];
    const unsigned char* mask = (const unsigned char*)d_in[3];
    const float* rel  = (const float*)d_in[4];
    const float* Wv   = (const float*)d_in[5];
    const float* bv   = (const float*)d_in[6];
    const float* Wk   = (const float*)d_in[7];
    const float* bk   = (const float*)d_in[8];
    const float* Wq   = (const float*)d_in[9];
    const float* bq   = (const float*)d_in[10];
    const float* Wr   = (const float*)d_in[11];
    const float* br   = (const float*)d_in[12];
    const float* Wm   = (const float*)d_in[13];
    const float* bm   = (const float*)d_in[14];

    const long long MB = 1 << 20;
    char* W = (char*)d_ws;
    unsigned short* xq    = (unsigned short*)(W + 0*MB);
    unsigned short* xk    = (unsigned short*)(W + 4*MB);
    unsigned short* xv    = (unsigned short*)(W + 8*MB);
    unsigned short* Wqb   = (unsigned short*)(W + 12*MB);
    unsigned short* Wkb   = (unsigned short*)(W + 14*MB);
    unsigned short* Wvb   = (unsigned short*)(W + 16*MB);
    unsigned short* Wmb   = (unsigned short*)(W + 18*MB);
    unsigned short* qhb   = (unsigned short*)(W + 20*MB);
    unsigned short* khb   = (unsigned short*)(W + 24*MB);
    unsigned short* vht   = (unsigned short*)(W + 28*MB);
    unsigned short* atted = (unsigned short*)(W + 32*MB);
    unsigned short* biasT = (unsigned short*)(W + 36*MB);  // 32 MB

    convert_kernel<<<10240, 256, 0, stream>>>(q, k, v, Wq, Wk, Wv, Wm, (unsigned short*)W);

    Gemm3 gp;
    gp.j[0] = { xq, Wqb, bq, (char*)qhb, 2 };
    gp.j[1] = { xk, Wkb, bk, (char*)khb, 1 };
    gp.j[2] = { xv, Wvb, bv, (char*)vht, 3 };
    gemm_rel<<<768 + 16384, 256, 0, stream>>>(gp, rel, Wr, br, biasT);

    attn_kernel<<<dim3(32, 16, 4), 256, 0, stream>>>(qhb, khb, vht, biasT, mask, atted);

    Gemm3 gf;
    gf.j[0] = { atted, Wmb, bm, (char*)d_out, 0 };
    gf.j[1] = gf.j[0];
    gf.j[2] = gf.j[0];
    gemm_bt<<<dim3(32, 8, 1), 256, 0, stream>>>(gf);
}

// Round 4
// 289.157 us; speedup vs baseline: 1.0578x; 1.0578x over previous
//
#include <hip/hip_runtime.h>
#include <hip/hip_bf16.h>
#include <stdint.h>

// RelMHAtt: B=4 S=512 HIDDEN=1024 H=16 D=64 R=64
// Pipeline: convert(fp32->bf16) -> fused [proj GEMM x3 || rel bias v3] ->
//           attention (register scores) -> out GEMM fp32.
// rel v3: coalesced float4 staging into XOR-swizzled rl[64][64]; thread =
// (k, h-quad); Wr chunks via wave-uniform global loads; accs in registers.

typedef __attribute__((ext_vector_type(8))) short bf16x8;
typedef __attribute__((ext_vector_type(4))) float f32x4;

__device__ inline unsigned short f2bf(float f) {
    __hip_bfloat16 h = __float2bfloat16(f);
    return *reinterpret_cast<unsigned short*>(&h);
}
__device__ inline float bf2f(unsigned short u) {
    unsigned int t = ((unsigned int)u) << 16;
    return __builtin_bit_cast(float, t);
}

// ---------------------------------------------------------------- convert
// dst layout (bf16): xq[2M] xk[2M] xv[2M] Wq[1M] Wk[1M] Wv[1M] Wm[1M]
__global__ __launch_bounds__(256) void convert_kernel(
    const float* __restrict__ q, const float* __restrict__ k, const float* __restrict__ v,
    const float* __restrict__ wq, const float* __restrict__ wk, const float* __restrict__ wv,
    const float* __restrict__ wm, unsigned short* __restrict__ dst)
{
    const long long X = 2097152LL, Wn = 1048576LL;
    long long e = 4LL * ((long long)blockIdx.x * 256 + threadIdx.x);
    const float* s;
    long long o = e;
    if      (o < X)          { s = q; }
    else if (o < 2*X)        { s = k;  o -= X; }
    else if (o < 3*X)        { s = v;  o -= 2*X; }
    else if (o < 3*X + Wn)   { s = wq; o -= 3*X; }
    else if (o < 3*X + 2*Wn) { s = wk; o -= 3*X + Wn; }
    else if (o < 3*X + 3*Wn) { s = wv; o -= 3*X + 2*Wn; }
    else                     { s = wm; o -= 3*X + 3*Wn; }
    float4 val = *reinterpret_cast<const float4*>(s + o);
    ushort4 u;
    u.x = f2bf(val.x); u.y = f2bf(val.y); u.z = f2bf(val.z); u.w = f2bf(val.w);
    *reinterpret_cast<ushort4*>(dst + e) = u;
}

// ---------------------------------------------------------------- GEMM defs
// C[m,n] = sum_k A[m,k]*B[n,k] + bias[n];  BM=64, BN=128, BK=32; 4 waves.
// mode 0: f32 [M,1024]; 1: bf16 [M,1024]; 2: bf16*0.125; 3: bf16 vht[b][h][d][s]
struct GemmJob { const unsigned short* A; const unsigned short* B; const float* bias; char* C; int mode; };
struct Gemm3 { GemmJob j[3]; };

// ---------------------------------------------------------------- fused proj GEMM + rel
// blocks [0,768): GEMM (z = bid>>8, m = (bid>>3)&31, n = bid&7)
// blocks [768, 768+16384): rel v3
//   biasT[b][h][q][k] = log(max(dot(rel[b,q,k,:], Wr[h,:]) + br[h], 1e-6))
__global__ __launch_bounds__(256) void gemm_rel(
    Gemm3 g, const float* __restrict__ rel, const float* __restrict__ Wr,
    const float* __restrict__ br, unsigned short* __restrict__ biasT)
{
    __shared__ union SM {
        struct { unsigned short As[2][2048]; unsigned short Bs[2][4096]; } gm;
        float rl[64][64];   // XOR-swizzled col-groups
    } sm;
    int tid = threadIdx.x;

    if (blockIdx.x < 768) {
        // ---------------- GEMM role ----------------
        int bid = blockIdx.x;
        GemmJob jb = g.j[bid >> 8];
        const unsigned short* __restrict__ A = jb.A;
        const unsigned short* __restrict__ B = jb.B;
        int bm0 = ((bid >> 3) & 31) * 64, bn0 = (bid & 7) * 128;
        int wid = tid >> 6, lane = tid & 63;
        int fr = lane & 15, fq = lane >> 4;
        int wm = (wid >> 1) * 32, wn = (wid & 1) * 64;

        f32x4 acc[2][4];
        f32x4 z4 = {0.f, 0.f, 0.f, 0.f};
        for (int i = 0; i < 2; i++) for (int j = 0; j < 4; j++) acc[i][j] = z4;

        auto stage = [&](int buf, int kt) {
            {
                int ci = tid;
                int row = ci >> 2, kc = ci & 3;
                const unsigned short* ga = A + (long long)(bm0 + row) * 1024 + kt * 32 + kc * 8;
                __builtin_amdgcn_global_load_lds((const __attribute__((address_space(1))) void*)ga,
                    (__attribute__((address_space(3))) void*)(&sm.gm.As[buf][ci * 8]), 16, 0, 0);
            }
            #pragma unroll
            for (int i = 0; i < 2; i++) {
                int ci = tid + 256 * i;
                int row = ci >> 2, kc = ci & 3;
                const unsigned short* gb = B + (long long)(bn0 + row) * 1024 + kt * 32 + kc * 8;
                __builtin_amdgcn_global_load_lds((const __attribute__((address_space(1))) void*)gb,
                    (__attribute__((address_space(3))) void*)(&sm.gm.Bs[buf][ci * 8]), 16, 0, 0);
            }
        };
        auto compute = [&](int buf) {
            bf16x8 a[2], b[4];
            #pragma unroll
            for (int fm = 0; fm < 2; fm++)
                a[fm] = *reinterpret_cast<const bf16x8*>(&sm.gm.As[buf][(wm + fm*16 + fr)*32 + fq*8]);
            #pragma unroll
            for (int fn = 0; fn < 4; fn++)
                b[fn] = *reinterpret_cast<const bf16x8*>(&sm.gm.Bs[buf][(wn + fn*16 + fr)*32 + fq*8]);
            #pragma unroll
            for (int fm = 0; fm < 2; fm++)
                #pragma unroll
                for (int fn = 0; fn < 4; fn++)
                    acc[fm][fn] = __builtin_amdgcn_mfma_f32_16x16x32_bf16(a[fm], b[fn], acc[fm][fn], 0, 0, 0);
        };

        stage(0, 0);
        asm volatile("s_waitcnt vmcnt(0)" ::: "memory");
        __syncthreads();
        int cur = 0;
        for (int kt = 0; kt < 31; kt++) {
            stage(cur ^ 1, kt + 1);
            compute(cur);
            asm volatile("s_waitcnt vmcnt(0)" ::: "memory");
            __syncthreads();
            cur ^= 1;
        }
        compute(cur);

        int mode = jb.mode;
        #pragma unroll
        for (int fm = 0; fm < 2; fm++) {
            #pragma unroll
            for (int fn = 0; fn < 4; fn++) {
                int col = bn0 + wn + fn*16 + fr;
                float bv = jb.bias[col];
                f32x4 vacc = acc[fm][fn];
                #pragma unroll
                for (int r = 0; r < 4; r++) {
                    int m = bm0 + wm + fm*16 + fq*4 + r;
                    float val = vacc[r] + bv;
                    if (mode == 0) {
                        reinterpret_cast<float*>(jb.C)[(long long)m*1024 + col] = val;
                    } else if (mode == 1) {
                        reinterpret_cast<unsigned short*>(jb.C)[(long long)m*1024 + col] = f2bf(val);
                    } else if (mode == 2) {
                        reinterpret_cast<unsigned short*>(jb.C)[(long long)m*1024 + col] = f2bf(val * 0.125f);
                    } else {
                        int bb = m >> 9, ss = m & 511;
                        int hh = col >> 6, dd = col & 63;
                        reinterpret_cast<unsigned short*>(jb.C)[(((long long)bb*16 + hh)*64 + dd)*512 + ss] = f2bf(val);
                    }
                }
            }
        }
    } else {
        // ---------------- rel v3 role ----------------
        int rid = blockIdx.x - 768;
        int k0 = (rid & 7) * 64;
        int q  = (rid >> 3) & 511;
        int b  = rid >> 12;
        const float* gsrc = rel + ((long long)(b*512 + q)*512 + k0) * 64;

        // stage 16KB tile: coalesced float4 loads, XOR-swizzled col-group store
        #pragma unroll
        for (int i = 0; i < 4; i++) {
            int ci = tid + 256*i;
            int row = ci >> 4, c4 = ci & 15;
            float4 v4 = *reinterpret_cast<const float4*>(gsrc + row*64 + c4*4);
            *reinterpret_cast<float4*>(&sm.rl[row][(c4 ^ (row & 15)) * 4]) = v4;
        }
        __syncthreads();

        int kk = tid & 63;          // this thread's k row (lane)
        int hq = tid >> 6;          // wave-uniform h-quad
        int h0 = hq * 4;
        float acc0 = br[h0], acc1 = br[h0+1], acc2 = br[h0+2], acc3 = br[h0+3];

        #pragma unroll
        for (int ch = 0; ch < 4; ch++) {
            float4 r[4];
            #pragma unroll
            for (int jj = 0; jj < 4; jj++) {
                int c4 = ch*4 + jj;
                r[jj] = *reinterpret_cast<const float4*>(&sm.rl[kk][(c4 ^ (kk & 15)) * 4]);
            }
            #pragma unroll
            for (int j = 0; j < 4; j++) {
                const float* wp = Wr + (h0 + j)*64 + ch*16;   // wave-uniform
                float a = 0.f;
                #pragma unroll
                for (int jj = 0; jj < 4; jj++) {
                    float4 w4 = *reinterpret_cast<const float4*>(wp + jj*4);
                    a += r[jj].x*w4.x + r[jj].y*w4.y + r[jj].z*w4.z + r[jj].w*w4.w;
                }
                if      (j == 0) acc0 += a;
                else if (j == 1) acc1 += a;
                else if (j == 2) acc2 += a;
                else             acc3 += a;
            }
        }

        long long base = ((long long)(b*16 + h0)*512 + q)*512 + k0 + kk;
        const long long HS = 512LL*512LL;
        biasT[base       ] = f2bf(__logf(fmaxf(acc0, 1e-6f)));
        biasT[base +   HS] = f2bf(__logf(fmaxf(acc1, 1e-6f)));
        biasT[base + 2*HS] = f2bf(__logf(fmaxf(acc2, 1e-6f)));
        biasT[base + 3*HS] = f2bf(__logf(fmaxf(acc3, 1e-6f)));
    }
}

// ---------------------------------------------------------------- final GEMM
__global__ __launch_bounds__(256) void gemm_bt(Gemm3 g)
{
    GemmJob jb = g.j[blockIdx.z];
    const unsigned short* __restrict__ A = jb.A;
    const unsigned short* __restrict__ B = jb.B;
    __shared__ alignas(16) unsigned short As[2][2048];
    __shared__ alignas(16) unsigned short Bs[2][4096];
    int tid = threadIdx.x;
    int bm0 = blockIdx.x * 64, bn0 = blockIdx.y * 128;
    int wid = tid >> 6, lane = tid & 63;
    int fr = lane & 15, fq = lane >> 4;
    int wm = (wid >> 1) * 32, wn = (wid & 1) * 64;

    f32x4 acc[2][4];
    f32x4 z4 = {0.f, 0.f, 0.f, 0.f};
    for (int i = 0; i < 2; i++) for (int j = 0; j < 4; j++) acc[i][j] = z4;

    auto stage = [&](int buf, int kt) {
        {
            int ci = tid;
            int row = ci >> 2, kc = ci & 3;
            const unsigned short* ga = A + (long long)(bm0 + row) * 1024 + kt * 32 + kc * 8;
            __builtin_amdgcn_global_load_lds((const __attribute__((address_space(1))) void*)ga,
                (__attribute__((address_space(3))) void*)(&As[buf][ci * 8]), 16, 0, 0);
        }
        #pragma unroll
        for (int i = 0; i < 2; i++) {
            int ci = tid + 256 * i;
            int row = ci >> 2, kc = ci & 3;
            const unsigned short* gb = B + (long long)(bn0 + row) * 1024 + kt * 32 + kc * 8;
            __builtin_amdgcn_global_load_lds((const __attribute__((address_space(1))) void*)gb,
                (__attribute__((address_space(3))) void*)(&Bs[buf][ci * 8]), 16, 0, 0);
        }
    };
    auto compute = [&](int buf) {
        bf16x8 a[2], b[4];
        #pragma unroll
        for (int fm = 0; fm < 2; fm++)
            a[fm] = *reinterpret_cast<const bf16x8*>(&As[buf][(wm + fm*16 + fr)*32 + fq*8]);
        #pragma unroll
        for (int fn = 0; fn < 4; fn++)
            b[fn] = *reinterpret_cast<const bf16x8*>(&Bs[buf][(wn + fn*16 + fr)*32 + fq*8]);
        #pragma unroll
        for (int fm = 0; fm < 2; fm++)
            #pragma unroll
            for (int fn = 0; fn < 4; fn++)
                acc[fm][fn] = __builtin_amdgcn_mfma_f32_16x16x32_bf16(a[fm], b[fn], acc[fm][fn], 0, 0, 0);
    };

    stage(0, 0);
    asm volatile("s_waitcnt vmcnt(0)" ::: "memory");
    __syncthreads();
    int cur = 0;
    for (int kt = 0; kt < 31; kt++) {
        stage(cur ^ 1, kt + 1);
        compute(cur);
        asm volatile("s_waitcnt vmcnt(0)" ::: "memory");
        __syncthreads();
        cur ^= 1;
    }
    compute(cur);

    int mode = jb.mode;
    #pragma unroll
    for (int fm = 0; fm < 2; fm++) {
        #pragma unroll
        for (int fn = 0; fn < 4; fn++) {
            int col = bn0 + wn + fn*16 + fr;
            float bv = jb.bias[col];
            f32x4 vacc = acc[fm][fn];
            #pragma unroll
            for (int r = 0; r < 4; r++) {
                int m = bm0 + wm + fm*16 + fq*4 + r;
                float val = vacc[r] + bv;
                if (mode == 0) {
                    reinterpret_cast<float*>(jb.C)[(long long)m*1024 + col] = val;
                } else if (mode == 1) {
                    reinterpret_cast<unsigned short*>(jb.C)[(long long)m*1024 + col] = f2bf(val);
                } else if (mode == 2) {
                    reinterpret_cast<unsigned short*>(jb.C)[(long long)m*1024 + col] = f2bf(val * 0.125f);
                } else {
                    int bb = m >> 9, ss = m & 511;
                    int hh = col >> 6, dd = col & 63;
                    reinterpret_cast<unsigned short*>(jb.C)[(((long long)bb*16 + hh)*64 + dd)*512 + ss] = f2bf(val);
                }
            }
        }
    }
}

// ---------------------------------------------------------------- attention
__global__ __launch_bounds__(256) void attn_kernel(
    const unsigned short* __restrict__ qh, const unsigned short* __restrict__ kh,
    const unsigned short* __restrict__ vht, const unsigned short* __restrict__ biasT,
    const unsigned char* __restrict__ mask, unsigned short* __restrict__ atted)
{
    __shared__ alignas(16) unsigned short Pl[16][520];
    __shared__ float pmax[4][16];
    __shared__ float psum[4][16];
    int tid = threadIdx.x;
    int wid = tid >> 6, lane = tid & 63;
    int fr = lane & 15, fq = lane >> 4;
    int q0 = blockIdx.x * 16;
    int h = blockIdx.y, b = blockIdx.z;

    bf16x8 aq[2];
    #pragma unroll
    for (int df = 0; df < 2; df++)
        aq[df] = *reinterpret_cast<const bf16x8*>(
            qh + (long long)(b*512 + q0 + fr)*1024 + h*64 + df*32 + fq*8);

    f32x4 s[8];
    #pragma unroll
    for (int kt = 0; kt < 8; kt++) {
        int cb = wid*128 + kt*16;
        f32x4 a4 = {0.f,0.f,0.f,0.f};
        #pragma unroll
        for (int df = 0; df < 2; df++) {
            bf16x8 bk = *reinterpret_cast<const bf16x8*>(
                kh + (long long)(b*512 + cb + fr)*1024 + h*64 + df*32 + fq*8);
            a4 = __builtin_amdgcn_mfma_f32_16x16x32_bf16(aq[df], bk, a4, 0, 0, 0);
        }
        s[kt] = a4;
    }

    const unsigned short* bbase = biasT + ((long long)(b*16 + h)*512 + q0)*512;
    #pragma unroll
    for (int kt = 0; kt < 8; kt++) {
        int col = wid*128 + kt*16 + fr;
        bool mk = mask[b*512 + col] != 0;
        #pragma unroll
        for (int r = 0; r < 4; r++) {
            float bias = bf2f(bbase[(fq*4 + r)*512 + col]);
            float val = s[kt][r] + bias;
            s[kt][r] = mk ? -1e9f : val;
        }
    }

    float rm[4];
    #pragma unroll
    for (int r = 0; r < 4; r++) {
        float m = s[0][r];
        #pragma unroll
        for (int kt = 1; kt < 8; kt++) m = fmaxf(m, s[kt][r]);
        #pragma unroll
        for (int x = 1; x < 16; x <<= 1) m = fmaxf(m, __shfl_xor(m, x, 64));
        rm[r] = m;
    }
    #pragma unroll
    for (int r = 0; r < 4; r++)
        if (fr == r) pmax[wid][fq*4 + r] = rm[r];
    __syncthreads();
    #pragma unroll
    for (int r = 0; r < 4; r++) {
        float m = pmax[0][fq*4 + r];
        m = fmaxf(m, pmax[1][fq*4 + r]);
        m = fmaxf(m, pmax[2][fq*4 + r]);
        m = fmaxf(m, pmax[3][fq*4 + r]);
        rm[r] = m;
    }

    float sum[4] = {0.f, 0.f, 0.f, 0.f};
    #pragma unroll
    for (int kt = 0; kt < 8; kt++) {
        int col = wid*128 + kt*16 + fr;
        #pragma unroll
        for (int r = 0; r < 4; r++) {
            float p = __expf(s[kt][r] - rm[r]);
            sum[r] += p;
            Pl[fq*4 + r][col] = f2bf(p);
        }
    }
    #pragma unroll
    for (int r = 0; r < 4; r++) {
        float sv = sum[r];
        #pragma unroll
        for (int x = 1; x < 16; x <<= 1) sv += __shfl_xor(sv, x, 64);
        sum[r] = sv;
    }
    #pragma unroll
    for (int r = 0; r < 4; r++)
        if (fr == r) psum[wid][fq*4 + r] = sum[r];
    __syncthreads();
    float sumr[4];
    #pragma unroll
    for (int r = 0; r < 4; r++)
        sumr[r] = psum[0][fq*4+r] + psum[1][fq*4+r] + psum[2][fq*4+r] + psum[3][fq*4+r];

    int d0 = wid * 16;
    f32x4 acco = {0.f,0.f,0.f,0.f};
    for (int c = 0; c < 16; c++) {
        bf16x8 pa = *reinterpret_cast<const bf16x8*>(&Pl[fr][c*32 + fq*8]);
        bf16x8 bv = *reinterpret_cast<const bf16x8*>(
            vht + ((long long)(b*16 + h)*64 + d0 + fr)*512 + c*32 + fq*8);
        acco = __builtin_amdgcn_mfma_f32_16x16x32_bf16(pa, bv, acco, 0, 0, 0);
    }
    #pragma unroll
    for (int r = 0; r < 4; r++) {
        float val = acco[r] / sumr[r];
        atted[(long long)(b*512 + q0 + fq*4 + r)*1024 + h*64 + d0 + fr] = f2bf(val);
    }
}

// ---------------------------------------------------------------- launch
extern "C" void kernel_launch(void* const* d_in, const int* in_sizes, int n_in,
                              void* d_out, int out_size, void* d_ws, size_t ws_size,
                              hipStream_t stream)
{
    const float* v    = (const float*)d_in[0];
    const float* k    = (const float*)d_in[1];
    const float* q    = (const float*)d_in[2];
    const unsigned char* mask = (const unsigned char*)d_in[3];
    const float* rel  = (const float*)d_in[4];
    const float* Wv   = (const float*)d_in[5];
    const float* bv   = (const float*)d_in[6];
    const float* Wk   = (const float*)d_in[7];
    const float* bk   = (const float*)d_in[8];
    const float* Wq   = (const float*)d_in[9];
    const float* bq   = (const float*)d_in[10];
    const float* Wr   = (const float*)d_in[11];
    const float* br   = (const float*)d_in[12];
    const float* Wm   = (const float*)d_in[13];
    const float* bm   = (const float*)d_in[14];

    const long long MB = 1 << 20;
    char* W = (char*)d_ws;
    unsigned short* xq    = (unsigned short*)(W + 0*MB);
    unsigned short* xk    = (unsigned short*)(W + 4*MB);
    unsigned short* xv    = (unsigned short*)(W + 8*MB);
    unsigned short* Wqb   = (unsigned short*)(W + 12*MB);
    unsigned short* Wkb   = (unsigned short*)(W + 14*MB);
    unsigned short* Wvb   = (unsigned short*)(W + 16*MB);
    unsigned short* Wmb   = (unsigned short*)(W + 18*MB);
    unsigned short* qhb   = (unsigned short*)(W + 20*MB);
    unsigned short* khb   = (unsigned short*)(W + 24*MB);
    unsigned short* vht   = (unsigned short*)(W + 28*MB);
    unsigned short* atted = (unsigned short*)(W + 32*MB);
    unsigned short* biasT = (unsigned short*)(W + 36*MB);  // 32 MB

    convert_kernel<<<10240, 256, 0, stream>>>(q, k, v, Wq, Wk, Wv, Wm, (unsigned short*)W);

    Gemm3 gp;
    gp.j[0] = { xq, Wqb, bq, (char*)qhb, 2 };
    gp.j[1] = { xk, Wkb, bk, (char*)khb, 1 };
    gp.j[2] = { xv, Wvb, bv, (char*)vht, 3 };
    gemm_rel<<<768 + 16384, 256, 0, stream>>>(gp, rel, Wr, br, biasT);

    attn_kernel<<<dim3(32, 16, 4), 256, 0, stream>>>(qhb, khb, vht, biasT, mask, atted);

    Gemm3 gf;
    gf.j[0] = { atted, Wmb, bm, (char*)d_out, 0 };
    gf.j[1] = gf.j[0];
    gf.j[2] = gf.j[0];
    gemm_bt<<<dim3(32, 8, 1), 256, 0, stream>>>(gf);
}

// Round 5
// 192.180 us; speedup vs baseline: 1.5917x; 1.5046x over previous
//
#include <hip/hip_runtime.h>
#include <hip/hip_bf16.h>
#include <stdint.h>

// RelMHAtt: B=4 S=512 HIDDEN=1024 H=16 D=64 R=64
// Split pipeline (R2 structure): convert(fp32->bf16) -> proj GEMM x3 ->
//   rel v4 (streaming, no rel LDS) -> attention (register scores) -> out GEMM.
// rel v4: 4 lanes per rel row (perfect 64B-line coalescing), Wr broadcast
// from LDS, acc[16] in regs, quad shfl-reduce. No staging of rel data.

typedef __attribute__((ext_vector_type(8))) short bf16x8;
typedef __attribute__((ext_vector_type(4))) float f32x4;

__device__ inline unsigned short f2bf(float f) {
    __hip_bfloat16 h = __float2bfloat16(f);
    return *reinterpret_cast<unsigned short*>(&h);
}
__device__ inline float bf2f(unsigned short u) {
    unsigned int t = ((unsigned int)u) << 16;
    return __builtin_bit_cast(float, t);
}

// ---------------------------------------------------------------- convert
// dst layout (bf16): xq[2M] xk[2M] xv[2M] Wq[1M] Wk[1M] Wv[1M] Wm[1M]
__global__ __launch_bounds__(256) void convert_kernel(
    const float* __restrict__ q, const float* __restrict__ k, const float* __restrict__ v,
    const float* __restrict__ wq, const float* __restrict__ wk, const float* __restrict__ wv,
    const float* __restrict__ wm, unsigned short* __restrict__ dst)
{
    const long long X = 2097152LL, Wn = 1048576LL;
    long long e = 4LL * ((long long)blockIdx.x * 256 + threadIdx.x);
    const float* s;
    long long o = e;
    if      (o < X)          { s = q; }
    else if (o < 2*X)        { s = k;  o -= X; }
    else if (o < 3*X)        { s = v;  o -= 2*X; }
    else if (o < 3*X + Wn)   { s = wq; o -= 3*X; }
    else if (o < 3*X + 2*Wn) { s = wk; o -= 3*X + Wn; }
    else if (o < 3*X + 3*Wn) { s = wv; o -= 3*X + 2*Wn; }
    else                     { s = wm; o -= 3*X + 3*Wn; }
    float4 val = *reinterpret_cast<const float4*>(s + o);
    ushort4 u;
    u.x = f2bf(val.x); u.y = f2bf(val.y); u.z = f2bf(val.z); u.w = f2bf(val.w);
    *reinterpret_cast<ushort4*>(dst + e) = u;
}

// ---------------------------------------------------------------- GEMM
// C[m,n] = sum_k A[m,k]*B[n,k] + bias[n];  BM=64, BN=128, BK=32; 4 waves.
// mode 0: f32 [M,1024]; 1: bf16 [M,1024]; 2: bf16*0.125; 3: bf16 vht[b][h][d][s]
struct GemmJob { const unsigned short* A; const unsigned short* B; const float* bias; char* C; int mode; };
struct Gemm3 { GemmJob j[3]; };

__global__ __launch_bounds__(256) void gemm_bt(Gemm3 g)
{
    GemmJob jb = g.j[blockIdx.z];
    const unsigned short* __restrict__ A = jb.A;
    const unsigned short* __restrict__ B = jb.B;
    __shared__ alignas(16) unsigned short As[2][2048];
    __shared__ alignas(16) unsigned short Bs[2][4096];
    int tid = threadIdx.x;
    int bm0 = blockIdx.x * 64, bn0 = blockIdx.y * 128;
    int wid = tid >> 6, lane = tid & 63;
    int fr = lane & 15, fq = lane >> 4;
    int wm = (wid >> 1) * 32, wn = (wid & 1) * 64;

    f32x4 acc[2][4];
    f32x4 z4 = {0.f, 0.f, 0.f, 0.f};
    for (int i = 0; i < 2; i++) for (int j = 0; j < 4; j++) acc[i][j] = z4;

    auto stage = [&](int buf, int kt) {
        {
            int ci = tid;
            int row = ci >> 2, kc = ci & 3;
            const unsigned short* ga = A + (long long)(bm0 + row) * 1024 + kt * 32 + kc * 8;
            __builtin_amdgcn_global_load_lds((const __attribute__((address_space(1))) void*)ga,
                (__attribute__((address_space(3))) void*)(&As[buf][ci * 8]), 16, 0, 0);
        }
        #pragma unroll
        for (int i = 0; i < 2; i++) {
            int ci = tid + 256 * i;
            int row = ci >> 2, kc = ci & 3;
            const unsigned short* gb = B + (long long)(bn0 + row) * 1024 + kt * 32 + kc * 8;
            __builtin_amdgcn_global_load_lds((const __attribute__((address_space(1))) void*)gb,
                (__attribute__((address_space(3))) void*)(&Bs[buf][ci * 8]), 16, 0, 0);
        }
    };
    auto compute = [&](int buf) {
        bf16x8 a[2], b[4];
        #pragma unroll
        for (int fm = 0; fm < 2; fm++)
            a[fm] = *reinterpret_cast<const bf16x8*>(&As[buf][(wm + fm*16 + fr)*32 + fq*8]);
        #pragma unroll
        for (int fn = 0; fn < 4; fn++)
            b[fn] = *reinterpret_cast<const bf16x8*>(&Bs[buf][(wn + fn*16 + fr)*32 + fq*8]);
        #pragma unroll
        for (int fm = 0; fm < 2; fm++)
            #pragma unroll
            for (int fn = 0; fn < 4; fn++)
                acc[fm][fn] = __builtin_amdgcn_mfma_f32_16x16x32_bf16(a[fm], b[fn], acc[fm][fn], 0, 0, 0);
    };

    stage(0, 0);
    asm volatile("s_waitcnt vmcnt(0)" ::: "memory");
    __syncthreads();
    int cur = 0;
    for (int kt = 0; kt < 31; kt++) {
        stage(cur ^ 1, kt + 1);
        compute(cur);
        asm volatile("s_waitcnt vmcnt(0)" ::: "memory");
        __syncthreads();
        cur ^= 1;
    }
    compute(cur);

    int mode = jb.mode;
    #pragma unroll
    for (int fm = 0; fm < 2; fm++) {
        #pragma unroll
        for (int fn = 0; fn < 4; fn++) {
            int col = bn0 + wn + fn*16 + fr;
            float bv = jb.bias[col];
            f32x4 vacc = acc[fm][fn];
            #pragma unroll
            for (int r = 0; r < 4; r++) {
                int m = bm0 + wm + fm*16 + fq*4 + r;
                float val = vacc[r] + bv;
                if (mode == 0) {
                    reinterpret_cast<float*>(jb.C)[(long long)m*1024 + col] = val;
                } else if (mode == 1) {
                    reinterpret_cast<unsigned short*>(jb.C)[(long long)m*1024 + col] = f2bf(val);
                } else if (mode == 2) {
                    reinterpret_cast<unsigned short*>(jb.C)[(long long)m*1024 + col] = f2bf(val * 0.125f);
                } else {
                    int bb = m >> 9, ss = m & 511;
                    int hh = col >> 6, dd = col & 63;
                    reinterpret_cast<unsigned short*>(jb.C)[(((long long)bb*16 + hh)*64 + dd)*512 + ss] = f2bf(val);
                }
            }
        }
    }
}

// ---------------------------------------------------------------- rel bias v4
// biasT[b][h][q][k] = log(max(dot(rel[b,q,k,:], Wr[h,:]) + br[h], 1e-6)) bf16.
// 4 lanes per row; lane cg covers chunks {4i+cg}; Wr broadcast from LDS;
// quad shfl-reduce; lane cg writes h in [cg*4, cg*4+4).
__global__ __launch_bounds__(256) void rel_kernel(
    const float* __restrict__ rel, const float* __restrict__ Wr, const float* __restrict__ br,
    unsigned short* __restrict__ biasT)
{
    __shared__ alignas(16) float wrs[16][64];
    int tid = threadIdx.x;
    {
        int h = tid >> 4, c4 = tid & 15;
        *reinterpret_cast<float4*>(&wrs[h][c4*4]) =
            *reinterpret_cast<const float4*>(Wr + h*64 + c4*4);
    }
    __syncthreads();

    long long row = (long long)blockIdx.x * 64 + (tid >> 2);
    int cg = tid & 3;
    const float* rp = rel + row*64 + cg*4;

    float acc[16];
    #pragma unroll
    for (int h = 0; h < 16; h++) acc[h] = 0.f;
    #pragma unroll
    for (int i = 0; i < 4; i++) {
        float4 r4 = *reinterpret_cast<const float4*>(rp + i*16);
        #pragma unroll
        for (int h = 0; h < 16; h++) {
            float4 w4 = *reinterpret_cast<const float4*>(&wrs[h][i*16 + cg*4]);
            acc[h] += r4.x*w4.x + r4.y*w4.y + r4.z*w4.z + r4.w*w4.w;
        }
    }
    #pragma unroll
    for (int h = 0; h < 16; h++) {
        acc[h] += __shfl_xor(acc[h], 1, 64);
        acc[h] += __shfl_xor(acc[h], 2, 64);
    }
    int b = (int)(row >> 18);
    int q = (int)((row >> 9) & 511);
    int k = (int)(row & 511);
    #pragma unroll
    for (int j = 0; j < 16; j++) {
        if ((j >> 2) == cg) {   // static acc index; predicated on lane's h-quad
            float val = acc[j] + br[j];
            biasT[(((long long)(b*16 + j)*512 + q) << 9) + k] = f2bf(__logf(fmaxf(val, 1e-6f)));
        }
    }
}

// ---------------------------------------------------------------- attention
__global__ __launch_bounds__(256) void attn_kernel(
    const unsigned short* __restrict__ qh, const unsigned short* __restrict__ kh,
    const unsigned short* __restrict__ vht, const unsigned short* __restrict__ biasT,
    const unsigned char* __restrict__ mask, unsigned short* __restrict__ atted)
{
    __shared__ alignas(16) unsigned short Pl[16][520];
    __shared__ float pmax[4][16];
    __shared__ float psum[4][16];
    int tid = threadIdx.x;
    int wid = tid >> 6, lane = tid & 63;
    int fr = lane & 15, fq = lane >> 4;
    int q0 = blockIdx.x * 16;
    int h = blockIdx.y, b = blockIdx.z;

    bf16x8 aq[2];
    #pragma unroll
    for (int df = 0; df < 2; df++)
        aq[df] = *reinterpret_cast<const bf16x8*>(
            qh + (long long)(b*512 + q0 + fr)*1024 + h*64 + df*32 + fq*8);

    f32x4 s[8];
    #pragma unroll
    for (int kt = 0; kt < 8; kt++) {
        int cb = wid*128 + kt*16;
        f32x4 a4 = {0.f,0.f,0.f,0.f};
        #pragma unroll
        for (int df = 0; df < 2; df++) {
            bf16x8 bk = *reinterpret_cast<const bf16x8*>(
                kh + (long long)(b*512 + cb + fr)*1024 + h*64 + df*32 + fq*8);
            a4 = __builtin_amdgcn_mfma_f32_16x16x32_bf16(aq[df], bk, a4, 0, 0, 0);
        }
        s[kt] = a4;
    }

    const unsigned short* bbase = biasT + ((long long)(b*16 + h)*512 + q0)*512;
    #pragma unroll
    for (int kt = 0; kt < 8; kt++) {
        int col = wid*128 + kt*16 + fr;
        bool mk = mask[b*512 + col] != 0;
        #pragma unroll
        for (int r = 0; r < 4; r++) {
            float bias = bf2f(bbase[(fq*4 + r)*512 + col]);
            float val = s[kt][r] + bias;
            s[kt][r] = mk ? -1e9f : val;
        }
    }

    float rm[4];
    #pragma unroll
    for (int r = 0; r < 4; r++) {
        float m = s[0][r];
        #pragma unroll
        for (int kt = 1; kt < 8; kt++) m = fmaxf(m, s[kt][r]);
        #pragma unroll
        for (int x = 1; x < 16; x <<= 1) m = fmaxf(m, __shfl_xor(m, x, 64));
        rm[r] = m;
    }
    #pragma unroll
    for (int r = 0; r < 4; r++)
        if (fr == r) pmax[wid][fq*4 + r] = rm[r];
    __syncthreads();
    #pragma unroll
    for (int r = 0; r < 4; r++) {
        float m = pmax[0][fq*4 + r];
        m = fmaxf(m, pmax[1][fq*4 + r]);
        m = fmaxf(m, pmax[2][fq*4 + r]);
        m = fmaxf(m, pmax[3][fq*4 + r]);
        rm[r] = m;
    }

    float sum[4] = {0.f, 0.f, 0.f, 0.f};
    #pragma unroll
    for (int kt = 0; kt < 8; kt++) {
        int col = wid*128 + kt*16 + fr;
        #pragma unroll
        for (int r = 0; r < 4; r++) {
            float p = __expf(s[kt][r] - rm[r]);
            sum[r] += p;
            Pl[fq*4 + r][col] = f2bf(p);
        }
    }
    #pragma unroll
    for (int r = 0; r < 4; r++) {
        float sv = sum[r];
        #pragma unroll
        for (int x = 1; x < 16; x <<= 1) sv += __shfl_xor(sv, x, 64);
        sum[r] = sv;
    }
    #pragma unroll
    for (int r = 0; r < 4; r++)
        if (fr == r) psum[wid][fq*4 + r] = sum[r];
    __syncthreads();
    float sumr[4];
    #pragma unroll
    for (int r = 0; r < 4; r++)
        sumr[r] = psum[0][fq*4+r] + psum[1][fq*4+r] + psum[2][fq*4+r] + psum[3][fq*4+r];

    int d0 = wid * 16;
    f32x4 acco = {0.f,0.f,0.f,0.f};
    for (int c = 0; c < 16; c++) {
        bf16x8 pa = *reinterpret_cast<const bf16x8*>(&Pl[fr][c*32 + fq*8]);
        bf16x8 bv = *reinterpret_cast<const bf16x8*>(
            vht + ((long long)(b*16 + h)*64 + d0 + fr)*512 + c*32 + fq*8);
        acco = __builtin_amdgcn_mfma_f32_16x16x32_bf16(pa, bv, acco, 0, 0, 0);
    }
    #pragma unroll
    for (int r = 0; r < 4; r++) {
        float val = acco[r] / sumr[r];
        atted[(long long)(b*512 + q0 + fq*4 + r)*1024 + h*64 + d0 + fr] = f2bf(val);
    }
}

// ---------------------------------------------------------------- launch
extern "C" void kernel_launch(void* const* d_in, const int* in_sizes, int n_in,
                              void* d_out, int out_size, void* d_ws, size_t ws_size,
                              hipStream_t stream)
{
    const float* v    = (const float*)d_in[0];
    const float* k    = (const float*)d_in[1];
    const float* q    = (const float*)d_in[2];
    const unsigned char* mask = (const unsigned char*)d_in[3];
    const float* rel  = (const float*)d_in[4];
    const float* Wv   = (const float*)d_in[5];
    const float* bv   = (const float*)d_in[6];
    const float* Wk   = (const float*)d_in[7];
    const float* bk   = (const float*)d_in[8];
    const float* Wq   = (const float*)d_in[9];
    const float* bq   = (const float*)d_in[10];
    const float* Wr   = (const float*)d_in[11];
    const float* br   = (const float*)d_in[12];
    const float* Wm   = (const float*)d_in[13];
    const float* bm   = (const float*)d_in[14];

    const long long MB = 1 << 20;
    char* W = (char*)d_ws;
    unsigned short* xq    = (unsigned short*)(W + 0*MB);
    unsigned short* xk    = (unsigned short*)(W + 4*MB);
    unsigned short* xv    = (unsigned short*)(W + 8*MB);
    unsigned short* Wqb   = (unsigned short*)(W + 12*MB);
    unsigned short* Wkb   = (unsigned short*)(W + 14*MB);
    unsigned short* Wvb   = (unsigned short*)(W + 16*MB);
    unsigned short* Wmb   = (unsigned short*)(W + 18*MB);
    unsigned short* qhb   = (unsigned short*)(W + 20*MB);
    unsigned short* khb   = (unsigned short*)(W + 24*MB);
    unsigned short* vht   = (unsigned short*)(W + 28*MB);
    unsigned short* atted = (unsigned short*)(W + 32*MB);
    unsigned short* biasT = (unsigned short*)(W + 36*MB);  // 32 MB

    convert_kernel<<<10240, 256, 0, stream>>>(q, k, v, Wq, Wk, Wv, Wm, (unsigned short*)W);

    Gemm3 gp;
    gp.j[0] = { xq, Wqb, bq, (char*)qhb, 2 };
    gp.j[1] = { xk, Wkb, bk, (char*)khb, 1 };
    gp.j[2] = { xv, Wvb, bv, (char*)vht, 3 };
    gemm_bt<<<dim3(32, 8, 3), 256, 0, stream>>>(gp);

    rel_kernel<<<16384, 256, 0, stream>>>(rel, Wr, br, biasT);

    attn_kernel<<<dim3(32, 16, 4), 256, 0, stream>>>(qhb, khb, vht, biasT, mask, atted);

    Gemm3 gf;
    gf.j[0] = { atted, Wmb, bm, (char*)d_out, 0 };
    gf.j[1] = gf.j[0];
    gf.j[2] = gf.j[0];
    gemm_bt<<<dim3(32, 8, 1), 256, 0, stream>>>(gf);
}